// Round 8
// baseline (26251.721 us; speedup 1.0000x reference)
//
#include <hip/hip_runtime.h>
#include <cstdint>
#include <cstddef>

// TransitionDown: FPS(8192 of 32768) + 16-NN + (Linear 64->128, BN, ReLU) + gather/maxpool
// R8: hang-free FPS pruning rewrite + scratch moved into d_out's y-region (ws footprint
// identical to R6-proven). k_fps3: no atomics, no dynamic loops; wave s&15 owns cell s;
// boxes/[st,en) in registers; ballot-driven dirty walk; 2 barriers/iter.
// FROZEN numerics (R5-PASS): d = fmaf(dz,dz,fmaf(dy,dy,dx*dx)) with __fsub_rn subs;
// fminf(old,d); kNN dot fma-asc + qq/pp fma chains; ties -> lowest original index.

#define TD_N 32768
#define TD_M 8192

__device__ __forceinline__ float sq3_fma(float a, float b, float c) {
  return fmaf(c, c, fmaf(b, b, __fmul_rn(a, a)));
}

__device__ __forceinline__ int cell_of(float x, float y, float z) {
  int ix = min(7, (int)(x * 8.0f));
  int iy = min(7, (int)(y * 8.0f));
  int iz = min(7, (int)(z * 8.0f));
  return (iz << 6) | (iy << 3) | ix;
}

// ---------------- K0: AoS -> SoA + |p|^2 (fma chain) ----------------
__global__ void k_soa(const float* __restrict__ p1, float* __restrict__ px,
                      float* __restrict__ py, float* __restrict__ pz,
                      float* __restrict__ pp) {
  int i = blockIdx.x * 256 + threadIdx.x;
  float a = p1[i * 3 + 0], b = p1[i * 3 + 1], c = p1[i * 3 + 2];
  px[i] = a; py[i] = b; pz[i] = c;
  pp[i] = sq3_fma(a, b, c);
}

// ---------------- K0b: histogram + prefix -> cell_start, cursor ----------------
__global__ __launch_bounds__(1024) void k_cells(const float* __restrict__ px,
                                                const float* __restrict__ py,
                                                const float* __restrict__ pz,
                                                int* __restrict__ cstart,
                                                int* __restrict__ cursor) {
  __shared__ int hist[512];
  __shared__ int wsum[16];
  int t = threadIdx.x;
  if (t < 512) hist[t] = 0;
  __syncthreads();
  for (int i = t; i < TD_N; i += 1024)
    atomicAdd(&hist[cell_of(px[i], py[i], pz[i])], 1);
  __syncthreads();
  int v = (t < 512) ? hist[t] : 0;
  int lane = t & 63, w = t >> 6;
  int s = v;
#pragma unroll
  for (int off = 1; off < 64; off <<= 1) {
    int o = __shfl_up(s, off);
    if (lane >= off) s += o;
  }
  if (lane == 63) wsum[w] = s;
  __syncthreads();
  if (t == 0) { int a = 0; for (int i = 0; i < 16; ++i) { int x = wsum[i]; wsum[i] = a; a += x; } }
  __syncthreads();
  int ex = s - v + wsum[w];
  if (t < 512) { cstart[t] = ex; cursor[t] = ex; }
  if (t == 0) cstart[512] = TD_N;
}

// ---------------- K0c: scatter into cell-sorted order ----------------
// Atomic order nondeterministic, but FPS outputs are order-invariant (elementwise
// min_d updates + original-index tie-breaks).
__global__ __launch_bounds__(256) void k_scatter(const float* __restrict__ px,
                                                 const float* __restrict__ py,
                                                 const float* __restrict__ pz,
                                                 int* __restrict__ cursor,
                                                 float* __restrict__ sx, float* __restrict__ sy,
                                                 float* __restrict__ sz, int* __restrict__ oidx) {
  int i = blockIdx.x * 256 + threadIdx.x;
  float X = px[i], Y = py[i], Z = pz[i];
  int c = cell_of(X, Y, Z);
  int pos = atomicAdd(&cursor[c], 1);
  sx[pos] = X; sy[pos] = Y; sz[pos] = Z; oidx[pos] = i;
}

// ---------------- K1: h = x@W + b, + per-block BN partial sums ----------------
__global__ __launch_bounds__(256) void k_mlp(const float* __restrict__ x,
                                             const float* __restrict__ W,
                                             const float* __restrict__ bias,
                                             float* __restrict__ h,
                                             float* __restrict__ part) {
  __shared__ float Wl[64 * 128];
  __shared__ float pl[4][2][128];
  int t = threadIdx.x;
#pragma unroll
  for (int i = 0; i < 8; ++i) {
    int f4 = t + i * 256;
    ((float4*)Wl)[f4] = ((const float4*)W)[f4];
  }
  __syncthreads();

  int rg = t >> 4;
  int ch = (t & 15) * 8;
  int row0 = blockIdx.x * 64 + rg * 4;

  float acc[4][8];
#pragma unroll
  for (int r = 0; r < 4; ++r)
#pragma unroll
    for (int c = 0; c < 8; ++c) acc[r][c] = 0.f;

  const float* xrow = x + (size_t)row0 * 64;
#pragma unroll 4
  for (int kc = 0; kc < 16; ++kc) {
    float xv[4][4];
#pragma unroll
    for (int r = 0; r < 4; ++r) {
      float4 t4 = *(const float4*)(xrow + r * 64 + kc * 4);
      xv[r][0] = t4.x; xv[r][1] = t4.y; xv[r][2] = t4.z; xv[r][3] = t4.w;
    }
#pragma unroll
    for (int kk = 0; kk < 4; ++kk) {
      int k = kc * 4 + kk;
      float4 wa = *(const float4*)&Wl[k * 128 + ch];
      float4 wb = *(const float4*)&Wl[k * 128 + ch + 4];
      float wv[8] = {wa.x, wa.y, wa.z, wa.w, wb.x, wb.y, wb.z, wb.w};
#pragma unroll
      for (int r = 0; r < 4; ++r)
#pragma unroll
        for (int c = 0; c < 8; ++c) acc[r][c] = fmaf(xv[r][kk], wv[c], acc[r][c]);
    }
  }

  float bv[8];
#pragma unroll
  for (int c = 0; c < 8; ++c) bv[c] = bias[ch + c];
  float s[8], q2[8];
#pragma unroll
  for (int c = 0; c < 8; ++c) { s[c] = 0.f; q2[c] = 0.f; }
#pragma unroll
  for (int r = 0; r < 4; ++r) {
    float hv[8];
#pragma unroll
    for (int c = 0; c < 8; ++c) hv[c] = acc[r][c] + bv[c];
    *(float4*)&h[(size_t)(row0 + r) * 128 + ch] = make_float4(hv[0], hv[1], hv[2], hv[3]);
    *(float4*)&h[(size_t)(row0 + r) * 128 + ch + 4] = make_float4(hv[4], hv[5], hv[6], hv[7]);
#pragma unroll
    for (int c = 0; c < 8; ++c) { s[c] += hv[c]; q2[c] = fmaf(hv[c], hv[c], q2[c]); }
  }
#pragma unroll
  for (int off = 16; off <= 32; off <<= 1) {
#pragma unroll
    for (int c = 0; c < 8; ++c) {
      s[c] += __shfl_xor(s[c], off);
      q2[c] += __shfl_xor(q2[c], off);
    }
  }
  int wv_ = t >> 6;
  if ((t & 63) < 16) {
#pragma unroll
    for (int c = 0; c < 8; ++c) { pl[wv_][0][ch + c] = s[c]; pl[wv_][1][ch + c] = q2[c]; }
  }
  __syncthreads();
  if (t < 128) {
    float S = 0.f, Q = 0.f;
#pragma unroll
    for (int w = 0; w < 4; ++w) { S += pl[w][0][t]; Q += pl[w][1][t]; }
    part[(size_t)blockIdx.x * 256 + t] = S;
    part[(size_t)blockIdx.x * 256 + 128 + t] = Q;
  }
}

// ---------------- K2: finalize BN -> scale/shift ----------------
__global__ void k_bn(const float* __restrict__ part, const float* __restrict__ gamma,
                     const float* __restrict__ beta, float* __restrict__ ss) {
  int t = threadIdx.x;  // 128
  float S = 0.f, Q = 0.f;
  for (int b = 0; b < 512; ++b) {
    S += part[(size_t)b * 256 + t];
    Q += part[(size_t)b * 256 + 128 + t];
  }
  float mean = S * (1.0f / 32768.0f);
  float var = Q * (1.0f / 32768.0f) - mean * mean;
  var = fmaxf(var, 0.0f);
  float inv = 1.0f / sqrtf(var + 1e-5f);
  float sc = gamma[t] * inv;
  ss[t] = sc;
  ss[128 + t] = beta[t] - mean * sc;
}

// ---------------- K3: FPS, pruned, ownership-partitioned (no atomics) ----------------
// Wave w owns cells {w, w+16, ..., w+496}; lane L<32 owns cell w+16L (slot 32w+L).
// Per iteration: lane-parallel prune check -> ballot -> wave walks its dirty cells.
// segv/segarg + md touched only by the owning wave between barriers => race-free.
__global__ __launch_bounds__(1024) void k_fps3(const float* __restrict__ sx,
                                               const float* __restrict__ sy,
                                               const float* __restrict__ sz,
                                               const int* __restrict__ oidx,
                                               const int* __restrict__ cstart,
                                               const float* __restrict__ px,
                                               const float* __restrict__ py,
                                               const float* __restrict__ pz,
                                               float* __restrict__ p2) {
  extern __shared__ float lds[];
  float* md   = lds;                    // 32768
  float* segv = lds + 32768;            // 512 (slot-indexed)
  int*   sega = (int*)(lds + 33280);    // 512
  float* rv   = lds + 33792;            // 16
  int*   ri   = (int*)(lds + 33808);    // 16  (total 33824 f = 135296 B)

  int t = threadIdx.x;
  int lane = t & 63, wid = t >> 6;

  for (int i = t; i < TD_N; i += 1024) md[i] = 1e10f;

  int myc  = wid + (lane << 4);   // lane<32: cell id 0..511
  int slot = (wid << 5) + lane;   // lane<32: 0..511, lane-contiguous per wave
  float bx0 = 1e30f, bx1 = -1e30f, by0 = 1e30f, by1 = -1e30f, bz0 = 1e30f, bz1 = -1e30f;
  int stR = 0, enR = 0;
  if (lane < 32) {
    stR = cstart[myc]; enR = cstart[myc + 1];
    stR = max(0, min(stR, TD_N));            // paranoia clamps (no-op when sane)
    enR = max(stR, min(enR, TD_N));
    for (int p = stR; p < enR; ++p) {
      float X = sx[p], Y = sy[p], Z = sz[p];
      bx0 = fminf(bx0, X); bx1 = fmaxf(bx1, X);
      by0 = fminf(by0, Y); by1 = fmaxf(by1, Y);
      bz0 = fminf(bz0, Z); bz1 = fmaxf(bz1, Z);
    }
    segv[slot] = (stR < enR) ? 1e10f : -1.0f;
    sega[slot] = 0x7fffffff;
  }
  float qx = px[0], qy = py[0], qz = pz[0];
  if (t == 0) { p2[0] = qx; p2[1] = qy; p2[2] = qz; }
  __syncthreads();

  for (int it = 1; it < TD_M; ++it) {
    // prune check: safe-skip when lb2*(1-1e-5) >= segmax (chain rel-err ~1e-6 << 1e-5
    // => every frozen d in cell provably > its md => no state change possible).
    bool isdirty = false;
    if (lane < 32) {
      float sm = segv[slot];
      float dxm = fmaxf(0.f, fmaxf(__fsub_rn(bx0, qx), __fsub_rn(qx, bx1)));
      float dym = fmaxf(0.f, fmaxf(__fsub_rn(by0, qy), __fsub_rn(qy, by1)));
      float dzm = fmaxf(0.f, fmaxf(__fsub_rn(bz0, qz), __fsub_rn(qz, bz1)));
      float lb2 = dxm * dxm + dym * dym + dzm * dzm;
      isdirty = !(lb2 * 0.99999f >= sm);
    }
    unsigned long long mask = __ballot(isdirty);
    while (mask) {
      int L = (int)__builtin_ctzll(mask);
      mask &= mask - 1;
      int st = __shfl(stR, L);
      int en = __shfl(enR, L);
      float bv = -1.0f; int bi = 0x7fffffff;
      for (int p0 = st; p0 < en; p0 += 64) {
        int p = p0 + lane;
        float nm = -1.0f; int oi = 0x7fffffff;
        if (p < en) {
          float dx = __fsub_rn(sx[p], qx);
          float dy = __fsub_rn(sy[p], qy);
          float dz = __fsub_rn(sz[p], qz);
          float d = fmaf(dz, dz, fmaf(dy, dy, __fmul_rn(dx, dx)));  // frozen chain
          float old = md[p];
          nm = fminf(old, d);
          md[p] = nm;
          oi = oidx[p];
        }
        if (nm > bv || (nm == bv && oi < bi)) { bv = nm; bi = oi; }
      }
#pragma unroll
      for (int off = 32; off; off >>= 1) {
        float ov = __shfl_xor(bv, off);
        int o2 = __shfl_xor(bi, off);
        if (ov > bv || (ov == bv && o2 < bi)) { bv = ov; bi = o2; }
      }
      if (lane == L) { segv[slot] = bv; sega[slot] = bi; }
    }
    __syncthreads();
    // tournament stage 1: 512 slots -> 16 per-wave winners
    {
      float v = (t < 512) ? segv[t] : -1.0f;
      int ix = (t < 512) ? sega[t] : 0x7fffffff;
#pragma unroll
      for (int off = 32; off; off >>= 1) {
        float ov = __shfl_xor(v, off);
        int o2 = __shfl_xor(ix, off);
        if (ov > v || (ov == v && o2 < ix)) { v = ov; ix = o2; }
      }
      if (lane == 0) { rv[wid] = v; ri[wid] = ix; }
    }
    __syncthreads();
    // stage 2 (all waves redundantly -> everyone learns q; no third barrier)
    {
      float v = rv[lane & 15];
      int ix = ri[lane & 15];
#pragma unroll
      for (int off = 8; off; off >>= 1) {
        float ov = __shfl_xor(v, off);
        int o2 = __shfl_xor(ix, off);
        if (ov > v || (ov == v && o2 < ix)) { v = ov; ix = o2; }
      }
      int ixc = ix & (TD_N - 1);  // paranoia clamp (no-op when sane)
      float wx = px[ixc], wy = py[ixc], wz = pz[ixc];
      if (t == 0) {
        p2[(size_t)it * 3 + 0] = wx;
        p2[(size_t)it * 3 + 1] = wy;
        p2[(size_t)it * 3 + 2] = wz;
      }
      qx = wx; qy = wy; qz = wz;
    }
    // no barrier: segv/sega next written only by owning waves after their own check;
    // rv/ri next written only after the scan-phase barrier above.
  }
}

// ---------------- K4: 16-NN — expanded f32, all-FMA chains (frozen from R5) ----------------
__device__ __forceinline__ unsigned long long shfl_xor_u64(unsigned long long v, int m) {
  unsigned lo = __shfl_xor((unsigned)v, m);
  unsigned hi = __shfl_xor((unsigned)(v >> 32), m);
  return ((unsigned long long)hi << 32) | lo;
}

__global__ __launch_bounds__(256) void k_knn(const float* __restrict__ px,
                                             const float* __restrict__ py,
                                             const float* __restrict__ pz,
                                             const float* __restrict__ pp,
                                             const float* __restrict__ p2,
                                             int* __restrict__ nb) {
  __shared__ unsigned long long mq[4][16][64];
  int wid = threadIdx.x >> 6, lane = threadIdx.x & 63;
  int q = blockIdx.x * 4 + wid;
  float qx = p2[(size_t)q * 3 + 0], qy = p2[(size_t)q * 3 + 1], qz = p2[(size_t)q * 3 + 2];
  float qq = sq3_fma(qx, qy, qz);

  unsigned long long sl[16];
#pragma unroll
  for (int s = 0; s < 16; ++s) sl[s] = ~0ULL;

#pragma unroll 2
  for (int c = 0; c < 512; ++c) {
    int i = c * 64 + lane;
    float X = px[i], Y = py[i], Z = pz[i], P = pp[i];
    float dot = fmaf(qz, Z, fmaf(qy, Y, __fmul_rn(qx, X)));       // fma-ascending
    float d2 = __fadd_rn(__fsub_rn(qq, __fadd_rn(dot, dot)), P);  // (qq - 2*dot) + pp
    unsigned u = __float_as_uint(d2);
    u ^= ((unsigned)(((int)u) >> 31)) | 0x80000000u;
    unsigned long long key = ((unsigned long long)u << 32) | (unsigned)i;
#pragma unroll
    for (int s = 0; s < 16; ++s) {
      unsigned long long lo = key < sl[s] ? key : sl[s];
      unsigned long long hi = key < sl[s] ? sl[s] : key;
      sl[s] = lo;
      key = hi;
    }
  }
#pragma unroll
  for (int s = 0; s < 16; ++s) mq[wid][s][lane] = sl[s];
  int head = 0;
  for (int r = 0; r < 16; ++r) {
    int hh = head < 16 ? head : 15;
    unsigned long long kk = mq[wid][hh][lane];
    if (head >= 16) kk = ~0ULL;
    unsigned long long v = kk;
#pragma unroll
    for (int off = 32; off; off >>= 1) {
      unsigned long long o = shfl_xor_u64(v, off);
      if (o < v) v = o;
    }
    if (kk == v) head++;
    if (lane == 0) nb[(size_t)q * 16 + r] = (int)(v & 0xffffffffULL);
  }
}

// ---------------- K5: gather + affine + relu + maxpool ----------------
__global__ __launch_bounds__(256) void k_gather(const float* __restrict__ h,
                                                const float* __restrict__ ss,
                                                const int* __restrict__ nb,
                                                float* __restrict__ y) {
  int t = threadIdx.x;
  int q = blockIdx.x * 2 + (t >> 7);
  int ch = t & 127;
  float sc = ss[ch], sh = ss[128 + ch];
  float m = -3.4e38f;
#pragma unroll
  for (int k = 0; k < 16; ++k) {
    int n = nb[(size_t)q * 16 + k];
    float v = h[(size_t)n * 128 + ch];
    m = fmaxf(m, fmaf(v, sc, sh));
  }
  y[(size_t)q * 128 + ch] = fmaxf(m, 0.0f);
}

extern "C" void kernel_launch(void* const* d_in, const int* in_sizes, int n_in,
                              void* d_out, int out_size, void* d_ws, size_t ws_size,
                              hipStream_t stream) {
  (void)in_sizes; (void)n_in; (void)out_size; (void)ws_size;
  const float* x = (const float*)d_in[0];
  const float* p1 = (const float*)d_in[1];
  const float* W = (const float*)d_in[2];
  const float* bias = (const float*)d_in[3];
  const float* gamma = (const float*)d_in[4];
  const float* beta = (const float*)d_in[5];

  float* out = (float*)d_out;
  float* y = out;                    // (8192,128)
  float* p2 = out + 1048576;         // (8192,3)

  // ws layout — IDENTICAL footprint to R6-proven (17,957,888 B):
  float* w = (float*)d_ws;
  float* h = w;                      // 4194304
  float* part = w + 4194304;         // 131072
  float* ss = w + 4325376;           // 256
  float* px = w + 4325632;           // 32768
  float* py = w + 4358400;
  float* pz = w + 4391168;
  float* pp = w + 4423936;
  int* nb = (int*)(w + 4456704);     // 8192*16 ints -> end 4489472 floats

  // FPS scratch lives in d_out's y-region (overwritten by k_gather at the very end):
  float* sx = y;                     // 32768
  float* sy = y + 32768;
  float* sz = y + 65536;
  int* oidx = (int*)(y + 98304);     // 32768
  int* cstart = (int*)(y + 131072);  // 513
  int* cursor = (int*)(y + 131648);  // 512  (end 132160 << 1048576)

  const int fps_lds = 135296;
  hipFuncSetAttribute((const void*)k_fps3, hipFuncAttributeMaxDynamicSharedMemorySize, fps_lds);

  k_soa<<<128, 256, 0, stream>>>(p1, px, py, pz, pp);
  k_cells<<<1, 1024, 0, stream>>>(px, py, pz, cstart, cursor);
  k_scatter<<<128, 256, 0, stream>>>(px, py, pz, cursor, sx, sy, sz, oidx);
  k_mlp<<<512, 256, 0, stream>>>(x, W, bias, h, part);
  k_bn<<<1, 128, 0, stream>>>(part, gamma, beta, ss);
  k_fps3<<<1, 1024, fps_lds, stream>>>(sx, sy, sz, oidx, cstart, px, py, pz, p2);
  k_knn<<<2048, 256, 0, stream>>>(px, py, pz, pp, p2, nb);
  k_gather<<<4096, 256, 0, stream>>>(h, ss, nb, y);
}